// Round 23
// baseline (360.392 us; speedup 1.0000x reference)
//
#include <hip/hip_runtime.h>

typedef _Float16 f16;
typedef __fp16 h2 __attribute__((ext_vector_type(2)));
typedef f16 f16x8 __attribute__((ext_vector_type(8)));
typedef float f32x4 __attribute__((ext_vector_type(4)));
typedef f32x4 __attribute__((aligned(4))) f32x4u;   // dword-aligned vector load
typedef float f32x16 __attribute__((ext_vector_type(16)));
typedef unsigned int uint32;

#define FIN  64
#define FOUT 64
#define HI   128
#define WI   128
#define HO   126
#define WO   126
#define HIWI (HI*WI)
#define TR   8       // tile rows
#define TC   16      // tile cols

// ws: B-fragment table f16 [i][ob][lane][8] = 128 KiB; Wc f16-pair table
// u32 [ipair][o] = 8 KiB at u32 offset 32768.
// k-labeling (validated rounds 6-22): k = g*4+(j&3)+8*(j>>2), g=lane>>5;
// taps k=4*dy+dx (dx<3 real, dx=3 zero-weight -> 4th float4 element is
// don't-care), k12 = bias (pixel side supplies 1.0h; k13..15 = 0).
// LESSONS (scratch traps): (r11) no address-of MFMA result vectors; (r12) no
// register arrays/acc by reference; (r14) VGPR budget; (r19) no ternary select
// on register structs; (r21) launch_bounds min-waves too high -> forced spill.
// r20->r23: ONLY change = depth-2 prefetch pipeline (c0,c1 in flight, load
// ip+2 per iter). All struct moves are by-value SSA; compute is a by-value ->
// by-value inlined function.

__global__ __launch_bounds__(256) void prepass(
    const float* __restrict__ Wf, const float* __restrict__ bf,
    const float* __restrict__ Wc, unsigned short* __restrict__ ws)
{
    int t = blockIdx.x * 256 + threadIdx.x;   // 0..10239
    if (t < 8192) {
        int i  = t >> 7;
        int ob = (t >> 6) & 1;
        int l  = t & 63;
        int g  = l >> 5, n = l & 31;
        int o  = ob * 32 + n;
        unsigned short h[8];
#pragma unroll
        for (int j = 0; j < 8; ++j) {
            int k = g * 4 + (j & 3) + 8 * (j >> 2);
            float v = 0.0f;
            if (k < 12) {
                int dy = k >> 2, dx = k & 3;
                if (dx < 3) v = Wf[((size_t)o * FIN + i) * 9 + dy * 3 + dx];
            } else if (k == 12) {
                v = bf[o * FIN + i];
            }
            f16 hv = (f16)v;
            h[j] = *(unsigned short*)&hv;
        }
        uint4 pk;
        pk.x = h[0] | ((uint32)h[1] << 16);
        pk.y = h[2] | ((uint32)h[3] << 16);
        pk.z = h[4] | ((uint32)h[5] << 16);
        pk.w = h[6] | ((uint32)h[7] << 16);
        *(uint4*)&ws[(size_t)t * 8] = pk;
    } else if (t < 8192 + 2048) {
        int t2 = t - 8192;
        int ip = t2 >> 6, o = t2 & 63;
        f16 lo = (f16)Wc[(size_t)o * FIN + 2 * ip];
        f16 hi = (f16)Wc[(size_t)o * FIN + 2 * ip + 1];
        uint32 v = (uint32)*(unsigned short*)&lo |
                   ((uint32)*(unsigned short*)&hi << 16);
        ((uint32*)ws)[32768 + t2] = v;
    }
}

// per-pair prefetch registers (by-value, SROA-safe; static indices only)
struct PR {
    f32x4 a1, a2;      // channel a: window rows (4 cols, 4th don't-care)
    f32x4 b1, b2;      // channel b
    uint4 aB, bB;      // B-fragments
    uint32 wcu;        // packed f16 Wc pair
};

__device__ __forceinline__ PR loadPair(const float* xb, const uint4* Btab,
                                       const uint32* wct, int ip,
                                       int goff1, int goff2, int oh, int l,
                                       int o_lane)
{
    PR r;
    const float* xa = xb + (size_t)(2 * ip) * HIWI;
    const float* xc = xa + HIWI;
    r.a1 = *(const f32x4u*)&xa[goff1];
    r.a2 = *(const f32x4u*)&xa[goff2];
    r.b1 = *(const f32x4u*)&xc[goff1];
    r.b2 = *(const f32x4u*)&xc[goff2];
    r.aB = Btab[(size_t)((2 * ip) * 2 + oh) * 64 + l];
    r.bB = Btab[(size_t)((2 * ip + 1) * 2 + oh) * 64 + l];
    r.wcu = wct[ip * 64 + o_lane];
    return r;
}

// all-by-value compute: returns updated accumulator (pure dataflow after inline)
__device__ __forceinline__ f32x16 computePair(PR cur, f32x16 acc,
                                              bool sel, int g)
{
    const f32x16 zero = {};
    const h2 zh = {(__fp16)0.0f, (__fp16)0.0f};

    float aw0 = sel ? cur.a1[1] : cur.a1[0];
    float aw1 = sel ? cur.a1[2] : cur.a1[1];
    float aw2 = sel ? cur.a1[3] : cur.a1[2];
    float av0 = sel ? cur.a2[1] : cur.a2[0];
    float av1 = sel ? cur.a2[2] : cur.a2[1];
    float av2 = sel ? cur.a2[3] : cur.a2[2];
    uint32 a0 = __builtin_bit_cast(uint32, __builtin_amdgcn_cvt_pkrtz(aw0, aw1));
    uint32 a1 = __builtin_bit_cast(uint32, __builtin_amdgcn_cvt_pkrtz(aw2, aw2));
    uint32 a2 = g ? 0x00003c00u
                  : __builtin_bit_cast(uint32, __builtin_amdgcn_cvt_pkrtz(av0, av1));
    uint32 a3 = g ? 0u
                  : __builtin_bit_cast(uint32, __builtin_amdgcn_cvt_pkrtz(av2, av2));
    uint4 av = {a0, a1, a2, a3};
    f32x16 S0 = __builtin_amdgcn_mfma_f32_32x32x16_f16(
        __builtin_bit_cast(f16x8, av), __builtin_bit_cast(f16x8, cur.aB),
        zero, 0, 0, 0);

    float bw0 = sel ? cur.b1[1] : cur.b1[0];
    float bw1 = sel ? cur.b1[2] : cur.b1[1];
    float bw2 = sel ? cur.b1[3] : cur.b1[2];
    float bv0 = sel ? cur.b2[1] : cur.b2[0];
    float bv1 = sel ? cur.b2[2] : cur.b2[1];
    float bv2 = sel ? cur.b2[3] : cur.b2[2];
    uint32 b0 = __builtin_bit_cast(uint32, __builtin_amdgcn_cvt_pkrtz(bw0, bw1));
    uint32 b1 = __builtin_bit_cast(uint32, __builtin_amdgcn_cvt_pkrtz(bw2, bw2));
    uint32 b2 = g ? 0x00003c00u
                  : __builtin_bit_cast(uint32, __builtin_amdgcn_cvt_pkrtz(bv0, bv1));
    uint32 b3 = g ? 0u
                  : __builtin_bit_cast(uint32, __builtin_amdgcn_cvt_pkrtz(bv2, bv2));
    uint4 bv = {b0, b1, b2, b3};
    f32x16 S1 = __builtin_amdgcn_mfma_f32_32x32x16_f16(
        __builtin_bit_cast(f16x8, bv), __builtin_bit_cast(f16x8, cur.bB),
        zero, 0, 0, 0);

    h2 wch = __builtin_bit_cast(h2, cur.wcu);
#pragma unroll
    for (int r = 0; r < 16; ++r) {
        h2 q = __builtin_amdgcn_cvt_pkrtz(S0[r], S1[r]);
        q = __builtin_elementwise_max(q, zh);
        acc[r] = __builtin_amdgcn_fdot2(q, wch, acc[r], false);
    }
    return acc;
}

__global__ __launch_bounds__(256, 4) void conv_mfma(
    const float* __restrict__ x,  const float* __restrict__ bc,
    const unsigned short* __restrict__ ws, float* __restrict__ out)
{
    __shared__ float ot[32][132];         // output transpose buffer only

    const int tid = threadIdx.x;          // 0..255, 4 waves
    const int l   = tid & 63, w = tid >> 6;
    const int g   = l >> 5;
    const int m   = l & 31;               // pixel idx on A; o on C/D
    const int prow = m >> 2;

    // XCD-group swizzle: all 16 blocks sharing (rx,b) -> same fid%8 (same XCD)
    const int fid    = blockIdx.x;
    const int grp    = (fid >> 7) * 8 + (fid & 7);   // 0..63 = rx + 16*b
    const int member = (fid >> 3) & 15;              // cy + 8*oh
    const int rx = grp & 15, b = grp >> 4;
    const int cy = member & 7, oh = member >> 3;
    const int row0 = rx * TR;
    const int col0 = cy * TC;
    const int o_lane = oh * 32 + m;

    // hoisted per-lane window offsets (clamps feed discarded outputs only)
    const int gy1 = min(row0 + prow + g, HI - 1);
    const int gy2 = min(row0 + prow + 2, HI - 1);
    const int ccr = col0 + w * 4 + (m & 3);          // raw window col (<=127)
    const int cc  = min(ccr, WI - 4);                // float4 base (<=124)
    const bool sel = (ccr > WI - 4);                 // shifted-window lanes
    const int goff1 = gy1 * WI + cc;
    const int goff2 = gy2 * WI + cc;

    const float*  xb   = x + (size_t)b * FIN * HIWI;
    const uint4*  Btab = (const uint4*)ws;
    const uint32* wct  = ((const uint32*)ws) + 32768;

    f32x16 acc = {};

    // depth-2 pipeline: c0, c1 in flight; load ip+2 while computing c0
    PR c0 = loadPair(xb, Btab, wct, 0, goff1, goff2, oh, l, o_lane);
    PR c1 = loadPair(xb, Btab, wct, 1, goff1, goff2, oh, l, o_lane);

#pragma unroll 2
    for (int ip = 0; ip < 30; ++ip) {
        PR n = loadPair(xb, Btab, wct, ip + 2, goff1, goff2, oh, l, o_lane);
        acc = computePair(c0, acc, sel, g);
        c0 = c1;
        c1 = n;
    }
    acc = computePair(c0, acc, sel, g);   // pair 30
    acc = computePair(c1, acc, sel, g);   // pair 31

    // ---- transpose: ot[o][px] then coalesced stores ----
    const float bcv = bc[o_lane];
#pragma unroll
    for (int r = 0; r < 16; ++r) {
        int p  = (r & 3) + 8 * (r >> 2) + 4 * g;             // wave-local pixel
        int px = (p >> 2) * TC + w * 4 + (p & 3);
        ot[m][px] = acc[r] + bcv;
    }
    __syncthreads();

    {
        const int oo  = tid >> 3;          // 0..31
        const int seg = tid & 7;           // tile row
        const int o   = oh * 32 + oo;
        const int ho  = row0 + seg;
        if (ho < HO) {
            const float* src = &ot[oo][seg * TC];
            size_t base = ((size_t)(b * FOUT + o) * HO + ho) * WO + col0;
            if (col0 + TC <= WO) {
#pragma unroll
                for (int c = 0; c < TC; ++c) out[base + c] = src[c];
            } else {
#pragma unroll
                for (int c = 0; c < 14; ++c) out[base + c] = src[c];
            }
        }
    }
}

extern "C" void kernel_launch(void* const* d_in, const int* in_sizes, int n_in,
                              void* d_out, int out_size, void* d_ws, size_t ws_size,
                              hipStream_t stream) {
    const float* x  = (const float*)d_in[0];
    const float* Wf = (const float*)d_in[1];
    const float* bf = (const float*)d_in[2];
    const float* Wc = (const float*)d_in[3];
    const float* bc = (const float*)d_in[4];
    float* out = (float*)d_out;
    unsigned short* ws = (unsigned short*)d_ws;

    hipLaunchKernelGGL(prepass, dim3(40), dim3(256), 0, stream, Wf, bf, Wc, ws);

    // 1024 blocks x 256 threads: 16 rx x (8 cy x 2 oh) x 4 b, XCD-group swizzled
    hipLaunchKernelGGL(conv_mfma, dim3(1024), dim3(256), 0, stream,
                       x, bc, ws, out);
}

// Round 24
// 40.471 us; speedup vs baseline: 8.9050x; 8.9050x over previous
//
#include <hip/hip_runtime.h>

typedef _Float16 f16;
typedef __fp16 h2 __attribute__((ext_vector_type(2)));
typedef f16 f16x8 __attribute__((ext_vector_type(8)));
typedef float f32x4 __attribute__((ext_vector_type(4)));
typedef f32x4 __attribute__((aligned(4))) f32x4u;   // dword-aligned vector load
typedef float f32x16 __attribute__((ext_vector_type(16)));
typedef unsigned int uint32;

#define FIN  64
#define FOUT 64
#define HI   128
#define WI   128
#define HO   126
#define WO   126
#define HIWI (HI*WI)
#define TR   8       // tile rows
#define TC   16      // tile cols

// ws: B-fragment table f16 [i][ob][lane][8] = 128 KiB; Wc f16-pair table
// u32 [ipair][o] = 8 KiB at u32 offset 32768.
// k-labeling (validated rounds 6-20): k = g*4+(j&3)+8*(j>>2), g=lane>>5;
// taps k=4*dy+dx (dx<3 real, dx=3 zero-weight -> 4th float4 element is
// don't-care), k12 = bias (pixel side supplies 1.0h; k13..15 = 0).
// LESSONS (scratch traps, each cost a round): (r11) no address-of MFMA result
// vectors; (r12) no register arrays by reference; (r14) VGPR budget; (r19) no
// ternary select on register structs; (r21) launch_bounds min-waves too high
// strangles the allocator; (r23) >=3 live prefetch structs -> allocas/spill.
// Loop = unconditional depth-1 prefetch + explicit tail (r18/r20 form).
// FINAL: r20 configuration — practical floor of this decomposition (40.5 us).

__global__ __launch_bounds__(256) void prepass(
    const float* __restrict__ Wf, const float* __restrict__ bf,
    const float* __restrict__ Wc, unsigned short* __restrict__ ws)
{
    int t = blockIdx.x * 256 + threadIdx.x;   // 0..10239
    if (t < 8192) {
        int i  = t >> 7;
        int ob = (t >> 6) & 1;
        int l  = t & 63;
        int g  = l >> 5, n = l & 31;
        int o  = ob * 32 + n;
        unsigned short h[8];
#pragma unroll
        for (int j = 0; j < 8; ++j) {
            int k = g * 4 + (j & 3) + 8 * (j >> 2);
            float v = 0.0f;
            if (k < 12) {
                int dy = k >> 2, dx = k & 3;
                if (dx < 3) v = Wf[((size_t)o * FIN + i) * 9 + dy * 3 + dx];
            } else if (k == 12) {
                v = bf[o * FIN + i];
            }
            f16 hv = (f16)v;
            h[j] = *(unsigned short*)&hv;
        }
        uint4 pk;
        pk.x = h[0] | ((uint32)h[1] << 16);
        pk.y = h[2] | ((uint32)h[3] << 16);
        pk.z = h[4] | ((uint32)h[5] << 16);
        pk.w = h[6] | ((uint32)h[7] << 16);
        *(uint4*)&ws[(size_t)t * 8] = pk;
    } else if (t < 8192 + 2048) {
        int t2 = t - 8192;
        int ip = t2 >> 6, o = t2 & 63;
        f16 lo = (f16)Wc[(size_t)o * FIN + 2 * ip];
        f16 hi = (f16)Wc[(size_t)o * FIN + 2 * ip + 1];
        uint32 v = (uint32)*(unsigned short*)&lo |
                   ((uint32)*(unsigned short*)&hi << 16);
        ((uint32*)ws)[32768 + t2] = v;
    }
}

// per-pair prefetch registers (by-value, SROA-safe; static indices only)
struct PR {
    f32x4 a1, a2;      // channel a: window rows (4 cols, 4th don't-care)
    f32x4 b1, b2;      // channel b
    uint4 aB, bB;      // B-fragments
    uint32 wcu;        // packed f16 Wc pair
};

__device__ __forceinline__ PR loadPair(const float* xb, const uint4* Btab,
                                       const uint32* wct, int ip,
                                       int goff1, int goff2, int oh, int l,
                                       int o_lane)
{
    PR r;
    const float* xa = xb + (size_t)(2 * ip) * HIWI;
    const float* xc = xa + HIWI;
    r.a1 = *(const f32x4u*)&xa[goff1];
    r.a2 = *(const f32x4u*)&xa[goff2];
    r.b1 = *(const f32x4u*)&xc[goff1];
    r.b2 = *(const f32x4u*)&xc[goff2];
    r.aB = Btab[(size_t)((2 * ip) * 2 + oh) * 64 + l];
    r.bB = Btab[(size_t)((2 * ip + 1) * 2 + oh) * 64 + l];
    r.wcu = wct[ip * 64 + o_lane];
    return r;
}

__global__ __launch_bounds__(256, 4) void conv_mfma(
    const float* __restrict__ x,  const float* __restrict__ bc,
    const unsigned short* __restrict__ ws, float* __restrict__ out)
{
    __shared__ float ot[32][132];         // output transpose buffer only

    const int tid = threadIdx.x;          // 0..255, 4 waves
    const int l   = tid & 63, w = tid >> 6;
    const int g   = l >> 5;
    const int m   = l & 31;               // pixel idx on A; o on C/D
    const int prow = m >> 2;

    // XCD-group swizzle: all 16 blocks sharing (rx,b) -> same fid%8 (same XCD)
    const int fid    = blockIdx.x;
    const int grp    = (fid >> 7) * 8 + (fid & 7);   // 0..63 = rx + 16*b
    const int member = (fid >> 3) & 15;              // cy + 8*oh
    const int rx = grp & 15, b = grp >> 4;
    const int cy = member & 7, oh = member >> 3;
    const int row0 = rx * TR;
    const int col0 = cy * TC;
    const int o_lane = oh * 32 + m;

    // hoisted per-lane window offsets (clamps feed discarded outputs only)
    const int gy1 = min(row0 + prow + g, HI - 1);
    const int gy2 = min(row0 + prow + 2, HI - 1);
    const int ccr = col0 + w * 4 + (m & 3);          // raw window col (<=127)
    const int cc  = min(ccr, WI - 4);                // float4 base (<=124)
    const bool sel = (ccr > WI - 4);                 // shifted-window lanes
    const int goff1 = gy1 * WI + cc;
    const int goff2 = gy2 * WI + cc;

    const float*  xb   = x + (size_t)b * FIN * HIWI;
    const uint4*  Btab = (const uint4*)ws;
    const uint32* wct  = ((const uint32*)ws) + 32768;

    f32x16 acc = {};
    const f32x16 zero = {};
    const h2 zh = {(__fp16)0.0f, (__fp16)0.0f};

    PR cur = loadPair(xb, Btab, wct, 0, goff1, goff2, oh, l, o_lane);

#pragma unroll 4
    for (int ip = 0; ip < 31; ++ip) {
        PR nxt = loadPair(xb, Btab, wct, ip + 1, goff1, goff2, oh, l, o_lane);

        // ---- compute current pair ----
        {
            float aw0 = sel ? cur.a1[1] : cur.a1[0];
            float aw1 = sel ? cur.a1[2] : cur.a1[1];
            float aw2 = sel ? cur.a1[3] : cur.a1[2];
            float av0 = sel ? cur.a2[1] : cur.a2[0];
            float av1 = sel ? cur.a2[2] : cur.a2[1];
            float av2 = sel ? cur.a2[3] : cur.a2[2];
            uint32 a0 = __builtin_bit_cast(uint32, __builtin_amdgcn_cvt_pkrtz(aw0, aw1));
            uint32 a1 = __builtin_bit_cast(uint32, __builtin_amdgcn_cvt_pkrtz(aw2, aw2));
            uint32 a2 = g ? 0x00003c00u
                          : __builtin_bit_cast(uint32, __builtin_amdgcn_cvt_pkrtz(av0, av1));
            uint32 a3 = g ? 0u
                          : __builtin_bit_cast(uint32, __builtin_amdgcn_cvt_pkrtz(av2, av2));
            uint4 av = {a0, a1, a2, a3};
            f32x16 S0 = __builtin_amdgcn_mfma_f32_32x32x16_f16(
                __builtin_bit_cast(f16x8, av), __builtin_bit_cast(f16x8, cur.aB),
                zero, 0, 0, 0);

            float bw0 = sel ? cur.b1[1] : cur.b1[0];
            float bw1 = sel ? cur.b1[2] : cur.b1[1];
            float bw2 = sel ? cur.b1[3] : cur.b1[2];
            float bv0 = sel ? cur.b2[1] : cur.b2[0];
            float bv1 = sel ? cur.b2[2] : cur.b2[1];
            float bv2 = sel ? cur.b2[3] : cur.b2[2];
            uint32 b0 = __builtin_bit_cast(uint32, __builtin_amdgcn_cvt_pkrtz(bw0, bw1));
            uint32 b1 = __builtin_bit_cast(uint32, __builtin_amdgcn_cvt_pkrtz(bw2, bw2));
            uint32 b2 = g ? 0x00003c00u
                          : __builtin_bit_cast(uint32, __builtin_amdgcn_cvt_pkrtz(bv0, bv1));
            uint32 b3 = g ? 0u
                          : __builtin_bit_cast(uint32, __builtin_amdgcn_cvt_pkrtz(bv2, bv2));
            uint4 bv = {b0, b1, b2, b3};
            f32x16 S1 = __builtin_amdgcn_mfma_f32_32x32x16_f16(
                __builtin_bit_cast(f16x8, bv), __builtin_bit_cast(f16x8, cur.bB),
                zero, 0, 0, 0);

            h2 wch = __builtin_bit_cast(h2, cur.wcu);
#pragma unroll
            for (int r = 0; r < 16; ++r) {
                h2 q = __builtin_amdgcn_cvt_pkrtz(S0[r], S1[r]);
                q = __builtin_elementwise_max(q, zh);
                acc[r] = __builtin_amdgcn_fdot2(q, wch, acc[r], false);
            }
        }
        cur = nxt;
    }
    // ---- last pair (ip = 31), identical body ----
    {
        float aw0 = sel ? cur.a1[1] : cur.a1[0];
        float aw1 = sel ? cur.a1[2] : cur.a1[1];
        float aw2 = sel ? cur.a1[3] : cur.a1[2];
        float av0 = sel ? cur.a2[1] : cur.a2[0];
        float av1 = sel ? cur.a2[2] : cur.a2[1];
        float av2 = sel ? cur.a2[3] : cur.a2[2];
        uint32 a0 = __builtin_bit_cast(uint32, __builtin_amdgcn_cvt_pkrtz(aw0, aw1));
        uint32 a1 = __builtin_bit_cast(uint32, __builtin_amdgcn_cvt_pkrtz(aw2, aw2));
        uint32 a2 = g ? 0x00003c00u
                      : __builtin_bit_cast(uint32, __builtin_amdgcn_cvt_pkrtz(av0, av1));
        uint32 a3 = g ? 0u
                      : __builtin_bit_cast(uint32, __builtin_amdgcn_cvt_pkrtz(av2, av2));
        uint4 av = {a0, a1, a2, a3};
        f32x16 S0 = __builtin_amdgcn_mfma_f32_32x32x16_f16(
            __builtin_bit_cast(f16x8, av), __builtin_bit_cast(f16x8, cur.aB),
            zero, 0, 0, 0);

        float bw0 = sel ? cur.b1[1] : cur.b1[0];
        float bw1 = sel ? cur.b1[2] : cur.b1[1];
        float bw2 = sel ? cur.b1[3] : cur.b1[2];
        float bv0 = sel ? cur.b2[1] : cur.b2[0];
        float bv1 = sel ? cur.b2[2] : cur.b2[1];
        float bv2 = sel ? cur.b2[3] : cur.b2[2];
        uint32 b0 = __builtin_bit_cast(uint32, __builtin_amdgcn_cvt_pkrtz(bw0, bw1));
        uint32 b1 = __builtin_bit_cast(uint32, __builtin_amdgcn_cvt_pkrtz(bw2, bw2));
        uint32 b2 = g ? 0x00003c00u
                      : __builtin_bit_cast(uint32, __builtin_amdgcn_cvt_pkrtz(bv0, bv1));
        uint32 b3 = g ? 0u
                      : __builtin_bit_cast(uint32, __builtin_amdgcn_cvt_pkrtz(bv2, bv2));
        uint4 bv = {b0, b1, b2, b3};
        f32x16 S1 = __builtin_amdgcn_mfma_f32_32x32x16_f16(
            __builtin_bit_cast(f16x8, bv), __builtin_bit_cast(f16x8, cur.bB),
            zero, 0, 0, 0);

        h2 wch = __builtin_bit_cast(h2, cur.wcu);
#pragma unroll
        for (int r = 0; r < 16; ++r) {
            h2 q = __builtin_amdgcn_cvt_pkrtz(S0[r], S1[r]);
            q = __builtin_elementwise_max(q, zh);
            acc[r] = __builtin_amdgcn_fdot2(q, wch, acc[r], false);
        }
    }

    // ---- transpose: ot[o][px] then coalesced stores ----
    const float bcv = bc[o_lane];
#pragma unroll
    for (int r = 0; r < 16; ++r) {
        int p  = (r & 3) + 8 * (r >> 2) + 4 * g;             // wave-local pixel
        int px = (p >> 2) * TC + w * 4 + (p & 3);
        ot[m][px] = acc[r] + bcv;
    }
    __syncthreads();

    {
        const int oo  = tid >> 3;          // 0..31
        const int seg = tid & 7;           // tile row
        const int o   = oh * 32 + oo;
        const int ho  = row0 + seg;
        if (ho < HO) {
            const float* src = &ot[oo][seg * TC];
            size_t base = ((size_t)(b * FOUT + o) * HO + ho) * WO + col0;
            if (col0 + TC <= WO) {
#pragma unroll
                for (int c = 0; c < TC; ++c) out[base + c] = src[c];
            } else {
#pragma unroll
                for (int c = 0; c < 14; ++c) out[base + c] = src[c];
            }
        }
    }
}

extern "C" void kernel_launch(void* const* d_in, const int* in_sizes, int n_in,
                              void* d_out, int out_size, void* d_ws, size_t ws_size,
                              hipStream_t stream) {
    const float* x  = (const float*)d_in[0];
    const float* Wf = (const float*)d_in[1];
    const float* bf = (const float*)d_in[2];
    const float* Wc = (const float*)d_in[3];
    const float* bc = (const float*)d_in[4];
    float* out = (float*)d_out;
    unsigned short* ws = (unsigned short*)d_ws;

    hipLaunchKernelGGL(prepass, dim3(40), dim3(256), 0, stream, Wf, bf, Wc, ws);

    // 1024 blocks x 256 threads: 16 rx x (8 cy x 2 oh) x 4 b, XCD-group swizzled
    hipLaunchKernelGGL(conv_mfma, dim3(1024), dim3(256), 0, stream,
                       x, bc, ws, out);
}